// Round 3
// baseline (153.550 us; speedup 1.0000x reference)
//
#include <hip/hip_runtime.h>

// ConvCaps EM-routing, MI355X. 392 independent problems, one 512-thread block each.
// Thread = (o = t&31 out-cap, kc = t>>5 of 16 k-chunks, 18 k each).
// M1 folded away (r·a/(Σr·a+eps) == r·c_k since Σ_o r == 1 always).
// E-step softmax fused via half-wave shuffles (o == lane index within 32-group).
// Moment partials: kc-pair combine via __shfl_xor(32) -> 8 LDS partial rows.

namespace {

constexpr int NKK = 288;
constexpr float EPSF = 1e-8f;
constexpr float LN2PI = 1.8378770664093453f;

__device__ __forceinline__ float fastrcp(float x) { return __builtin_amdgcn_rcpf(x); }

__global__ __launch_bounds__(512, 4)
void caps_em_kernel(const float* __restrict__ x,
                    const float* __restrict__ Wg,
                    const float* __restrict__ bu,
                    const float* __restrict__ ba,
                    float* __restrict__ out)
{
    // LDS: 18432 + 1152 + 38016 + 17408 + 2048 + 2048 + 640 = 79744 B -> 2 blocks/CU
    __shared__ float p4[NKK * 16];       // pose fragments [k*16+p]
    __shared__ float cIn[NKK];           // a/(a+eps)
    __shared__ float rbuf[NKK * 33];     // r (includes c_k factor), padded stride 33
    __shared__ float scr[8 * 544];       // 8 kc2 x 32 o x (16+1)
    __shared__ float meanS[512];         // mean[o*16+p]
    __shared__ float i2vS[512];          // 1/(2*std^2)
    __shared__ float rsumS[32];
    __shared__ float invrsS[32];
    __shared__ float s1S[32];
    __shared__ float actS[32];
    __shared__ float baseS[32];          // -sum_p log std - 8*ln2pi + log(act)

    const int n = blockIdx.x;
    const int t = threadIdx.x;

    // ---- gather poses: flat view of tiled (B,kh,kw,oh,ow,512) ----
    for (int idx = t; idx < NKK * 16; idx += 512) {
        unsigned g = (unsigned)n * 4608u + (unsigned)idx;
        unsigned c = g & 511u, rest = g >> 9;
        unsigned ow = rest % 7u; rest /= 7u;
        unsigned oh = rest % 7u; rest /= 7u;
        unsigned kw = rest % 3u; rest /= 3u;
        unsigned kh = rest % 3u;
        unsigned b  = rest / 3u;
        p4[idx] = x[((b*16u + 2u*oh + kh)*16u + 2u*ow + kw)*544u + c];
    }
    // ---- gather acts -> c_k = a/(a+eps) ----
    for (int idx = t; idx < NKK; idx += 512) {
        unsigned g = (unsigned)n * 288u + (unsigned)idx;
        unsigned c = g & 31u, rest = g >> 5;
        unsigned ow = rest % 7u; rest /= 7u;
        unsigned oh = rest % 7u; rest /= 7u;
        unsigned kw = rest % 3u; rest /= 3u;
        unsigned kh = rest % 3u;
        unsigned b  = rest / 3u;
        const float a = x[((b*16u + 2u*oh + kh)*16u + 2u*ow + kw)*544u + 512u + c];
        cIn[idx] = a / (a + EPSF);
    }
    __syncthreads();
    for (int idx = t; idx < NKK * 32; idx += 512)
        rbuf[(idx >> 5)*33 + (idx & 31)] = 0.03125f * cIn[idx >> 5];
    __syncthreads();

    const int o  = t & 31;    // out-cap (== lane index within 32-group)
    const int kc = t >> 5;    // k-chunk 0..15 (18 k each)

    float lam = 1.0e-3f;
    float Sv[16], Sv2[16];

    for (int it = 0; it < 3; ++it) {
        lam += 1.0e-4f;

        // ---- r_sum[o] over k ----
        {
            float s = 0.f;
            #pragma unroll 6
            for (int kk = 0; kk < 18; ++kk) s += rbuf[(kc*18 + kk)*33 + o];
            scr[kc*32 + o] = s;
        }
        __syncthreads();
        if (t < 32) {
            float rs = 0.f;
            #pragma unroll
            for (int q = 0; q < 16; ++q) rs += scr[q*32 + t];
            rsumS[t] = rs;
            const float inv = 1.0f / (rs + EPSF);
            invrsS[t] = inv;
            s1S[t] = rs * inv;
        }
        __syncthreads();

        // ---- M-step: one-pass weighted moments of recomputed votes ----
        #pragma unroll
        for (int p = 0; p < 16; ++p) { Sv[p] = 0.f; Sv2[p] = 0.f; }
        {
            const float irs = invrsS[o];
            #pragma unroll 2
            for (int kk = 0; kk < 18; ++kk) {
                const int k = kc*18 + kk;
                const float w = rbuf[k*33 + o] * irs;   // r_prob
                float P[16], Wl[16];
                #pragma unroll
                for (int p = 0; p < 16; p += 4) {
                    const float4 v4 = *(const float4*)&p4[k*16 + p];
                    P[p] = v4.x; P[p+1] = v4.y; P[p+2] = v4.z; P[p+3] = v4.w;
                    const float4 w4 = *(const float4*)&Wg[(k*32 + o)*16 + p];
                    Wl[p] = w4.x; Wl[p+1] = w4.y; Wl[p+2] = w4.z; Wl[p+3] = w4.w;
                }
                #pragma unroll
                for (int i = 0; i < 4; ++i) {
                    #pragma unroll
                    for (int m = 0; m < 4; ++m) {
                        float v = P[i*4] * Wl[m];
                        v = fmaf(P[i*4+1], Wl[4+m],  v);
                        v = fmaf(P[i*4+2], Wl[8+m],  v);
                        v = fmaf(P[i*4+3], Wl[12+m], v);
                        const float wv = w * v;
                        Sv [i*4+m] += wv;
                        Sv2[i*4+m]  = fmaf(wv, v, Sv2[i*4+m]);
                    }
                }
            }
        }
        // combine kc pairs (partner = lane^32, same wave) -> 8 partial groups
        #pragma unroll
        for (int p = 0; p < 16; ++p) {
            Sv [p] += __shfl_xor(Sv [p], 32, 64);
            Sv2[p] += __shfl_xor(Sv2[p], 32, 64);
        }
        if ((kc & 1) == 0) {
            #pragma unroll
            for (int p = 0; p < 16; ++p) scr[((kc >> 1)*32 + o)*17 + p] = Sv[p];
        }
        __syncthreads();
        {
            const int oo = t >> 4, pp = t & 15;
            float s = 0.f;
            #pragma unroll
            for (int q = 0; q < 8; ++q) s += scr[(q*32 + oo)*17 + pp];
            meanS[t] = s;
        }
        __syncthreads();
        if ((kc & 1) == 0) {
            #pragma unroll
            for (int p = 0; p < 16; ++p) scr[((kc >> 1)*32 + o)*17 + p] = Sv2[p];
        }
        __syncthreads();
        {
            const int oo = t >> 4, pp = t & 15;
            float s2 = 0.f;
            #pragma unroll
            for (int q = 0; q < 8; ++q) s2 += scr[(q*32 + oo)*17 + pp];
            const float m = meanS[t];
            // sum r_prob*(v-m)^2 = E[wv^2] - m^2*(2 - S1)
            float var = s2 - m*m*(2.0f - s1S[oo]);
            var = fmaxf(var, 0.0f) + EPSF;          // std^2 (+eps inside sqrt)
            i2vS[t] = 0.5f / var;
            scr[oo*17 + pp] = 0.5f * __logf(var);   // log(std); q=0 slot owned by this thread
        }
        __syncthreads();
        if (t < 32) {
            float lsum = 0.f;
            #pragma unroll
            for (int p = 0; p < 16; ++p) lsum += scr[t*17 + p];
            const float rs   = rsumS[t];
            const float cost = (16.0f * bu[t] + lsum) * rs;
            const float ao   = 1.0f / (1.0f + __expf(-lam * (ba[t] - cost)));
            actS[t]  = ao;
            baseS[t] = -lsum - 8.0f*LN2PI + __logf(ao);
        }
        __syncthreads();

        if (it == 2) break;

        // ---- E-step with fused per-k softmax over o (half-wave shuffles) ----
        {
            float M[16], I[16];
            #pragma unroll
            for (int p = 0; p < 16; ++p) { M[p] = meanS[o*16 + p]; I[p] = i2vS[o*16 + p]; }
            const float base = baseS[o];
            #pragma unroll 2
            for (int kk = 0; kk < 18; ++kk) {
                const int k = kc*18 + kk;
                float P[16], Wl[16];
                #pragma unroll
                for (int p = 0; p < 16; p += 4) {
                    const float4 v4 = *(const float4*)&p4[k*16 + p];
                    P[p] = v4.x; P[p+1] = v4.y; P[p+2] = v4.z; P[p+3] = v4.w;
                    const float4 w4 = *(const float4*)&Wg[(k*32 + o)*16 + p];
                    Wl[p] = w4.x; Wl[p+1] = w4.y; Wl[p+2] = w4.z; Wl[p+3] = w4.w;
                }
                float sacc = 0.f;
                #pragma unroll
                for (int i = 0; i < 4; ++i) {
                    #pragma unroll
                    for (int m = 0; m < 4; ++m) {
                        float v = P[i*4] * Wl[m];
                        v = fmaf(P[i*4+1], Wl[4+m],  v);
                        v = fmaf(P[i*4+2], Wl[8+m],  v);
                        v = fmaf(P[i*4+3], Wl[12+m], v);
                        const float d = v - M[i*4+m];
                        sacc = fmaf(d*d, I[i*4+m], sacc);
                    }
                }
                float lnp = base - sacc;
                // softmax over the 32 o's living in this 32-lane group
                float mx = lnp;
                #pragma unroll
                for (int d = 1; d < 32; d <<= 1) mx = fmaxf(mx, __shfl_xor(mx, d, 64));
                const float e = __expf(lnp - mx);
                float ssum = e;
                #pragma unroll
                for (int d = 1; d < 32; d <<= 1) ssum += __shfl_xor(ssum, d, 64);
                rbuf[k*33 + o] = e * cIn[k] * fastrcp(ssum);  // fold next M1's c_k
            }
        }
        __syncthreads();
    }

    // ---- output: [mean(512) | act(32)] per n ----
    for (int idx = t; idx < 544; idx += 512) {
        const float v = (idx < 512) ? meanS[idx] : actS[idx - 512];
        out[n*544 + idx] = v;
    }
}

} // namespace

extern "C" void kernel_launch(void* const* d_in, const int* in_sizes, int n_in,
                              void* d_out, int out_size, void* d_ws, size_t ws_size,
                              hipStream_t stream) {
    (void)in_sizes; (void)n_in; (void)out_size; (void)d_ws; (void)ws_size;
    const float* x  = (const float*)d_in[0];
    const float* W  = (const float*)d_in[1];
    const float* bu = (const float*)d_in[2];
    const float* ba = (const float*)d_in[3];
    float* out = (float*)d_out;
    caps_em_kernel<<<dim3(392), dim3(512), 0, stream>>>(x, W, bu, ba, out);
}

// Round 4
// 130.002 us; speedup vs baseline: 1.1811x; 1.1811x over previous
//
#include <hip/hip_runtime.h>

// ConvCaps EM-routing, MI355X. 392 independent problems, one 512-thread block each.
// Thread = (o = t&31 out-cap, kc = t>>5 of 16 k-chunks, 18 k each).
// Fused E+M: votes recomputed only 3x (M0, E0+M1, E1+M2) using unnormalized
// moments  mean = S(uv)/(rs+eps), var = S(uv^2)/(rs+eps) - m^2(2-S1),
// u_k = softmax_o(ln_ap)*c_k, c_k = a/(a+eps). r-matrix never materialized.

namespace {

constexpr int NKK = 288;
constexpr float EPSF = 1e-8f;
constexpr float LN2PI = 1.8378770664093453f;

__device__ __forceinline__ float fastrcp(float x) { return __builtin_amdgcn_rcpf(x); }

__global__ __launch_bounds__(512, 4)
void caps_em_kernel(const float* __restrict__ x,
                    const float* __restrict__ Wg,
                    const float* __restrict__ bu,
                    const float* __restrict__ ba,
                    float* __restrict__ out)
{
    // LDS: 18432 + 1152 + 33792 + 2176 + 2176 + 256 = 57984 B -> 2 blocks/CU
    __shared__ float p4[NKK * 16];       // pose fragments [k*16+p]
    __shared__ float cIn[NKK];           // a/(a+eps)
    __shared__ float scr[8 * 32 * 33];   // [g][o][ Sv(16) | Sv2(16) | S0 ]
    __shared__ float meanS[32 * 17];     // mean[o*17+p]  (stride 17: conflict-free)
    __shared__ float i2vS[32 * 17];      // 1/(2*std^2)
    __shared__ float actS[32];
    __shared__ float baseS[32];          // log(act) - sum_p log std - 8*ln2pi

    const int n = blockIdx.x;
    const int t = threadIdx.x;

    // ---- gather poses: flat view of tiled (B,kh,kw,oh,ow,512) ----
    for (int idx = t; idx < NKK * 16; idx += 512) {
        unsigned g = (unsigned)n * 4608u + (unsigned)idx;
        unsigned c = g & 511u, rest = g >> 9;
        unsigned ow = rest % 7u; rest /= 7u;
        unsigned oh = rest % 7u; rest /= 7u;
        unsigned kw = rest % 3u; rest /= 3u;
        unsigned kh = rest % 3u;
        unsigned b  = rest / 3u;
        p4[idx] = x[((b*16u + 2u*oh + kh)*16u + 2u*ow + kw)*544u + c];
    }
    // ---- gather acts -> c_k ----
    for (int idx = t; idx < NKK; idx += 512) {
        unsigned g = (unsigned)n * 288u + (unsigned)idx;
        unsigned c = g & 31u, rest = g >> 5;
        unsigned ow = rest % 7u; rest /= 7u;
        unsigned oh = rest % 7u; rest /= 7u;
        unsigned kw = rest % 3u; rest /= 3u;
        unsigned kh = rest % 3u;
        unsigned b  = rest / 3u;
        const float a = x[((b*16u + 2u*oh + kh)*16u + 2u*ow + kw)*544u + 512u + c];
        cIn[idx] = a / (a + EPSF);
    }
    __syncthreads();

    const int o  = t & 31;    // out-cap (== lane&31)
    const int kc = t >> 5;    // k-chunk 0..15 (18 k each)
    const int oo = t >> 4;    // reducer row 0..31
    const int pp = t & 15;    // reducer col 0..15

    float lam = 1.0e-3f;

    for (int it = 0; it < 3; ++it) {
        lam += 1.0e-4f;

        float S0 = 0.f, Sv[16], Sv2[16];
        #pragma unroll
        for (int p = 0; p < 16; ++p) { Sv[p] = 0.f; Sv2[p] = 0.f; }

        if (it == 0) {
            // ---- M0: uniform r -> u_k = c_k/32 (same for all o) ----
            #pragma unroll 2
            for (int kk = 0; kk < 18; ++kk) {
                const int k = kc*18 + kk;
                const float w = cIn[k] * 0.03125f;
                float P[16], Wl[16];
                #pragma unroll
                for (int p = 0; p < 16; p += 4) {
                    const float4 v4 = *(const float4*)&p4[k*16 + p];
                    P[p] = v4.x; P[p+1] = v4.y; P[p+2] = v4.z; P[p+3] = v4.w;
                    const float4 w4 = *(const float4*)&Wg[(k*32 + o)*16 + p];
                    Wl[p] = w4.x; Wl[p+1] = w4.y; Wl[p+2] = w4.z; Wl[p+3] = w4.w;
                }
                S0 += w;
                #pragma unroll
                for (int i = 0; i < 4; ++i) {
                    #pragma unroll
                    for (int m = 0; m < 4; ++m) {
                        float v = P[i*4] * Wl[m];
                        v = fmaf(P[i*4+1], Wl[4+m],  v);
                        v = fmaf(P[i*4+2], Wl[8+m],  v);
                        v = fmaf(P[i*4+3], Wl[12+m], v);
                        const float wv = w * v;
                        Sv [i*4+m] += wv;
                        Sv2[i*4+m]  = fmaf(wv, v, Sv2[i*4+m]);
                    }
                }
            }
        } else {
            // ---- fused E(prev stats) + M accumulate ----
            float M[16], I[16];
            #pragma unroll
            for (int p = 0; p < 16; ++p) { M[p] = meanS[o*17 + p]; I[p] = i2vS[o*17 + p]; }
            const float base = baseS[o];
            for (int kk = 0; kk < 18; ++kk) {
                const int k = kc*18 + kk;
                float P[16], Wl[16];
                #pragma unroll
                for (int p = 0; p < 16; p += 4) {
                    const float4 v4 = *(const float4*)&p4[k*16 + p];
                    P[p] = v4.x; P[p+1] = v4.y; P[p+2] = v4.z; P[p+3] = v4.w;
                    const float4 w4 = *(const float4*)&Wg[(k*32 + o)*16 + p];
                    Wl[p] = w4.x; Wl[p+1] = w4.y; Wl[p+2] = w4.z; Wl[p+3] = w4.w;
                }
                float v[16];
                float sacc = 0.f;
                #pragma unroll
                for (int i = 0; i < 4; ++i) {
                    #pragma unroll
                    for (int m = 0; m < 4; ++m) {
                        float vv = P[i*4] * Wl[m];
                        vv = fmaf(P[i*4+1], Wl[4+m],  vv);
                        vv = fmaf(P[i*4+2], Wl[8+m],  vv);
                        vv = fmaf(P[i*4+3], Wl[12+m], vv);
                        v[i*4+m] = vv;
                        const float d = vv - M[i*4+m];
                        sacc = fmaf(d*d, I[i*4+m], sacc);
                    }
                }
                const float lnp = base - sacc;
                // softmax over the 32 o's in this half-wave
                float mx = lnp;
                #pragma unroll
                for (int d = 1; d < 32; d <<= 1) mx = fmaxf(mx, __shfl_xor(mx, d, 64));
                const float e = __expf(lnp - mx);
                float ss = e;
                #pragma unroll
                for (int d = 1; d < 32; d <<= 1) ss += __shfl_xor(ss, d, 64);
                const float u = e * fastrcp(ss) * cIn[k];
                S0 += u;
                #pragma unroll
                for (int p = 0; p < 16; ++p) {
                    const float uv = u * v[p];
                    Sv [p] += uv;
                    Sv2[p]  = fmaf(uv, v[p], Sv2[p]);
                }
            }
        }

        // ---- combine kc pairs (partner lane^32, same wave) -> 8 groups ----
        S0 += __shfl_xor(S0, 32, 64);
        #pragma unroll
        for (int p = 0; p < 16; ++p) {
            Sv [p] += __shfl_xor(Sv [p], 32, 64);
            Sv2[p] += __shfl_xor(Sv2[p], 32, 64);
        }
        if ((kc & 1) == 0) {
            float* row = &scr[((kc >> 1)*32 + o)*33];
            #pragma unroll
            for (int p = 0; p < 16; ++p) { row[p] = Sv[p]; row[16 + p] = Sv2[p]; }
            row[32] = S0;
        }
        __syncthreads();

        // ---- reduce 8 groups + stats; thread t handles (oo, pp) ----
        {
            float sm = 0.f, s2 = 0.f, rs = 0.f;
            #pragma unroll
            for (int q = 0; q < 8; ++q) {
                const int b0 = (q*32 + oo)*33;
                sm += scr[b0 + pp];
                s2 += scr[b0 + 16 + pp];
                rs += scr[b0 + 32];
            }
            const float inv = 1.0f / (rs + EPSF);
            const float S1  = rs * inv;
            const float m   = sm * inv;
            float var = s2 * inv - m*m*(2.0f - S1);
            var = fmaxf(var, 0.0f) + EPSF;          // std^2 (+eps inside sqrt)
            meanS[oo*17 + pp] = m;
            i2vS [oo*17 + pp] = 0.5f / var;
            scr[oo*33 + pp] = 0.5f * __logf(var);   // log std; q=0 slot owned by this thread
        }
        __syncthreads();
        if (t < 32) {
            float lsum = 0.f;
            #pragma unroll
            for (int p = 0; p < 16; ++p) lsum += scr[t*33 + p];
            float rs = 0.f;
            #pragma unroll
            for (int q = 0; q < 8; ++q) rs += scr[(q*32 + t)*33 + 32];
            const float cost = (16.0f * bu[t] + lsum) * rs;
            const float ao   = 1.0f / (1.0f + __expf(-lam * (ba[t] - cost)));
            actS[t]  = ao;
            baseS[t] = -lsum - 8.0f*LN2PI + __logf(ao);
        }
        __syncthreads();
    }

    // ---- output: [mean(512) | act(32)] per n ----
    for (int idx = t; idx < 544; idx += 512) {
        const float v = (idx < 512) ? meanS[(idx >> 4)*17 + (idx & 15)]
                                    : actS[idx - 512];
        out[n*544 + idx] = v;
    }
}

} // namespace

extern "C" void kernel_launch(void* const* d_in, const int* in_sizes, int n_in,
                              void* d_out, int out_size, void* d_ws, size_t ws_size,
                              hipStream_t stream) {
    (void)in_sizes; (void)n_in; (void)out_size; (void)d_ws; (void)ws_size;
    const float* x  = (const float*)d_in[0];
    const float* W  = (const float*)d_in[1];
    const float* bu = (const float*)d_in[2];
    const float* ba = (const float*)d_in[3];
    float* out = (float*)d_out;
    caps_em_kernel<<<dim3(392), dim3(512), 0, stream>>>(x, W, bu, ba, out);
}